// Round 3
// baseline (596.456 us; speedup 1.0000x reference)
//
#include <hip/hip_runtime.h>
#include <hip/hip_bf16.h>

typedef __bf16 bf16x8 __attribute__((ext_vector_type(8)));
typedef float  f32x4  __attribute__((ext_vector_type(4)));

#define GRU_H 128
#define ROWS  32          // rows staged per block iteration
#define LDSP  132         // padded row stride (floats): +4 keeps 16B align, spreads banks

__device__ inline bf16x8 frag_from_lds(const float* p) {
    float4 a = *reinterpret_cast<const float4*>(p);
    float4 b = *reinterpret_cast<const float4*>(p + 4);
    bf16x8 r;
    r[0] = (__bf16)a.x; r[1] = (__bf16)a.y; r[2] = (__bf16)a.z; r[3] = (__bf16)a.w;
    r[4] = (__bf16)b.x; r[5] = (__bf16)b.y; r[6] = (__bf16)b.z; r[7] = (__bf16)b.w;
    return r;
}

__device__ inline bf16x8 frag_from_global(const float* p) { return frag_from_lds(p); }

__device__ inline float sigmoidf_(float x) { return 1.f / (1.f + __expf(-x)); }
__device__ inline float tanhf_(float x)    { return 1.f - 2.f / (__expf(2.f * x) + 1.f); }

// Reverse-order copy: runs BEFORE the GRU scatter; reversed so low rows are the
// most recently touched -> L3-resident when gru gathers rows 0..B.
__global__ __launch_bounds__(256) void copy_rev_kernel(const float4* __restrict__ src,
                                                       float4* __restrict__ dst, size_t n4) {
    size_t stride = (size_t)gridDim.x * 256;
    for (size_t i = (size_t)blockIdx.x * 256 + threadIdx.x; i < n4; i += stride) {
        size_t j = n4 - 1 - i;           // contiguous within a wave, just descending
        dst[j] = src[j];
    }
}

// 512 threads = 8 waves. Wave w owns column tile w (16 of 128 cols); its 6 gate
// weight slices live in registers (loaded once). Per iteration the BLOCK stages
// 32 rows of messages + gathered memory rows into LDS (coalesced, once), then
// each wave runs 2x (16-row sub-tile): 24 mfma_16x16x32_bf16 + gate epilogue,
// reading h from LDS, scatter-storing to out[node_ids[row]].
__global__ __launch_bounds__(512, 2) void gru_update_kernel(
    const int*   __restrict__ node_ids,
    const float* __restrict__ messages,
    const float* __restrict__ memory,
    const float* __restrict__ W_ih,
    const float* __restrict__ W_hh,
    const float* __restrict__ b_ih,
    const float* __restrict__ b_hh,
    float*       __restrict__ out,
    int B)
{
    __shared__ float xs[ROWS][LDSP];
    __shared__ float hs[ROWS][LDSP];
    __shared__ int   ids[ROWS];

    const int wave = threadIdx.x >> 6;
    const int lane = threadIdx.x & 63;
    const int l15  = lane & 15;
    const int lg   = lane >> 4;          // 0..3
    const int col  = wave * 16 + l15;

    // B-fragments: B[k][n] = W[gate*128 + n][k]; n = l15 (==col within tile),
    // k = ks*32 + lg*8 + i.
    bf16x8 bfrag[6][4];
    #pragma unroll
    for (int g = 0; g < 3; ++g)
        #pragma unroll
        for (int ks = 0; ks < 4; ++ks) {
            const int off = (g * GRU_H + col) * GRU_H + ks * 32 + lg * 8;
            bfrag[g][ks]     = frag_from_global(W_ih + off);
            bfrag[g + 3][ks] = frag_from_global(W_hh + off);
        }
    const float bi_r = b_ih[col], bi_z = b_ih[GRU_H + col], bi_n = b_ih[2 * GRU_H + col];
    const float bh_r = b_hh[col], bh_z = b_hh[GRU_H + col], bh_n = b_hh[2 * GRU_H + col];

    const int nchunks = (B + ROWS - 1) / ROWS;
    for (int c = blockIdx.x; c < nchunks; c += gridDim.x) {
        const int rb = c * ROWS;

        // ---- stage 32 rows of x and gathered h into LDS (2 float4/thread each)
        #pragma unroll
        for (int s = 0; s < 2; ++s) {
            const int f4  = threadIdx.x + s * 512;   // 0..1023
            const int row = f4 >> 5;                 // 32 float4 per row
            const int c4  = f4 & 31;
            const int grow = rb + row;
            if (grow < B) {
                const int gid = node_ids[grow];
                if (c4 == 0) ids[row] = gid;
                *reinterpret_cast<float4*>(&xs[row][c4 * 4]) =
                    *reinterpret_cast<const float4*>(&messages[(size_t)grow * GRU_H + c4 * 4]);
                *reinterpret_cast<float4*>(&hs[row][c4 * 4]) =
                    *reinterpret_cast<const float4*>(&memory[(size_t)gid * GRU_H + c4 * 4]);
            } else {
                float4 z = {0.f, 0.f, 0.f, 0.f};
                *reinterpret_cast<float4*>(&xs[row][c4 * 4]) = z;
                *reinterpret_cast<float4*>(&hs[row][c4 * 4]) = z;
            }
        }
        __syncthreads();

        // ---- two 16-row sub-tiles per wave
        #pragma unroll
        for (int sub = 0; sub < 2; ++sub) {
            const int rbase = sub * 16;

            bf16x8 ax[4], ah[4];
            #pragma unroll
            for (int ks = 0; ks < 4; ++ks) {
                ax[ks] = frag_from_lds(&xs[rbase + l15][ks * 32 + lg * 8]);
                ah[ks] = frag_from_lds(&hs[rbase + l15][ks * 32 + lg * 8]);
            }

            f32x4 acc[6];
            #pragma unroll
            for (int g = 0; g < 6; ++g) acc[g] = (f32x4){0.f, 0.f, 0.f, 0.f};

            #pragma unroll
            for (int ks = 0; ks < 4; ++ks) {
                acc[0] = __builtin_amdgcn_mfma_f32_16x16x32_bf16(ax[ks], bfrag[0][ks], acc[0], 0, 0, 0);
                acc[1] = __builtin_amdgcn_mfma_f32_16x16x32_bf16(ax[ks], bfrag[1][ks], acc[1], 0, 0, 0);
                acc[2] = __builtin_amdgcn_mfma_f32_16x16x32_bf16(ax[ks], bfrag[2][ks], acc[2], 0, 0, 0);
                acc[3] = __builtin_amdgcn_mfma_f32_16x16x32_bf16(ah[ks], bfrag[3][ks], acc[3], 0, 0, 0);
                acc[4] = __builtin_amdgcn_mfma_f32_16x16x32_bf16(ah[ks], bfrag[4][ks], acc[4], 0, 0, 0);
                acc[5] = __builtin_amdgcn_mfma_f32_16x16x32_bf16(ah[ks], bfrag[5][ks], acc[5], 0, 0, 0);
            }

            // D layout: col = l15, row = lg*4 + r
            #pragma unroll
            for (int r = 0; r < 4; ++r) {
                const int row  = rbase + lg * 4 + r;
                const int grow = rb + row;
                if (grow < B) {
                    const int gid = ids[row];
                    const float h  = hs[row][col];
                    const float rg = sigmoidf_((acc[0][r] + bi_r) + (acc[3][r] + bh_r));
                    const float zg = sigmoidf_((acc[1][r] + bi_z) + (acc[4][r] + bh_z));
                    const float ng = tanhf_((acc[2][r] + bi_n) + rg * (acc[5][r] + bh_n));
                    out[(size_t)gid * GRU_H + col] = (1.f - zg) * ng + zg * h;
                }
            }
        }
        __syncthreads();
    }
}

extern "C" void kernel_launch(void* const* d_in, const int* in_sizes, int n_in,
                              void* d_out, int out_size, void* d_ws, size_t ws_size,
                              hipStream_t stream) {
    const int*   node_ids = (const int*)d_in[0];
    const float* messages = (const float*)d_in[1];
    const float* memory   = (const float*)d_in[2];
    const float* W_ih     = (const float*)d_in[3];
    const float* W_hh     = (const float*)d_in[4];
    const float* b_ih     = (const float*)d_in[5];
    const float* b_hh     = (const float*)d_in[6];
    float* out = (float*)d_out;

    const int B = in_sizes[0];                  // 100000
    const int N = in_sizes[2] / GRU_H;          // 500000

    // 1) pass-through copy memory -> out (own kernel; memcpy node was ~1.2 TB/s SDMA)
    const size_t n4 = (size_t)N * GRU_H / 4;
    copy_rev_kernel<<<2048, 256, 0, stream>>>((const float4*)memory, (float4*)out, n4);

    // 2) GRU update + scatter (overwrites updated rows)
    const int nchunks = (B + ROWS - 1) / ROWS;
    int grid = nchunks < 1024 ? nchunks : 1024;
    gru_update_kernel<<<grid, 512, 0, stream>>>(node_ids, messages, memory,
                                                W_ih, W_hh, b_ih, b_hh, out, B);
}

// Round 5
// 533.077 us; speedup vs baseline: 1.1189x; 1.1189x over previous
//
#include <hip/hip_runtime.h>
#include <hip/hip_bf16.h>

typedef __bf16 bf16x8 __attribute__((ext_vector_type(8)));
typedef float  f32x4  __attribute__((ext_vector_type(4)));

#define GRU_H 128
#define ROWS  64           // rows staged per block iteration
#define NTHR  512          // 8 waves

__device__ inline float sigmoidf_(float x) { return 1.f / (1.f + __expf(-x)); }
__device__ inline float tanhf_(float x)    { return 1.f - 2.f / (__expf(2.f * x) + 1.f); }

__device__ inline bf16x8 cvt8(float4 a, float4 b) {
    bf16x8 r;
    r[0] = (__bf16)a.x; r[1] = (__bf16)a.y; r[2] = (__bf16)a.z; r[3] = (__bf16)a.w;
    r[4] = (__bf16)b.x; r[5] = (__bf16)b.y; r[6] = (__bf16)b.z; r[7] = (__bf16)b.w;
    return r;
}

// ---- 1) weights f32 -> bf16 lane-ordered MFMA fragments in ws; also zero flag.
// frag t = ((wave*6+g)*4+ks)*64+lane : 8 bf16 of W[(g%3)*128+col][ks*32+lg*8 ..+7]
__global__ __launch_bounds__(512) void convert_weights(
    const float* __restrict__ W_ih, const float* __restrict__ W_hh,
    bf16x8* __restrict__ frags, int* __restrict__ flag)
{
    if (blockIdx.x == 0 && threadIdx.x == 0) *flag = 0;
    const int t = blockIdx.x * 512 + threadIdx.x;       // 0..12287
    const int lane = t & 63;
    const int ks   = (t >> 6) & 3;
    const int r    = t >> 8;                            // 0..47
    const int g    = r % 6;
    const int wave = r / 6;
    const int col  = wave * 16 + (lane & 15);
    const int lg   = lane >> 4;
    const int gg   = (g < 3) ? g : g - 3;
    const float* src = ((g < 3) ? W_ih : W_hh) + ((size_t)(gg * GRU_H + col)) * GRU_H + ks * 32 + lg * 8;
    float4 a = *reinterpret_cast<const float4*>(src);
    float4 b = *reinterpret_cast<const float4*>(src + 4);
    frags[t] = cvt8(a, b);
}

// ---- 2) verify node_ids == arange (enables copy skip of rows < B)
__global__ __launch_bounds__(256) void check_arange(const int* __restrict__ ids, int B,
                                                    int* __restrict__ flag)
{
    int bad = 0;
    for (int i = blockIdx.x * 256 + threadIdx.x; i < B; i += gridDim.x * 256)
        bad |= (ids[i] != i);
    if (bad) atomicOr(flag, 1);
}

// ---- 3) pass-through copy; skips rows [0,B) when flag==0 (gru writes them)
__global__ __launch_bounds__(256) void copy_skip(const float4* __restrict__ src,
                                                 float4* __restrict__ dst,
                                                 size_t n4, size_t skip4,
                                                 const int* __restrict__ flag)
{
    const size_t start  = (*flag == 0) ? skip4 : 0;
    const size_t stride = (size_t)gridDim.x * 256;
    for (size_t i = start + (size_t)blockIdx.x * 256 + threadIdx.x; i < n4; i += stride)
        dst[i] = src[i];
}

// ---- 4) GRU update + scatter. 8 waves; wave w owns 16-col tile; weights are
// register-resident bf16 frags from ws. Per block-iter: stage 64 rows (x as
// bf16, h as f32; both XOR-swizzled at 16B granularity), 4 sub-tiles of
// 24x mfma_16x16x32_bf16 + gate epilogue, scatter to out[node_ids[row]].
__global__ __launch_bounds__(512, 2) void gru_update_kernel(
    const int*   __restrict__ node_ids,
    const float* __restrict__ messages,
    const float* __restrict__ memory,
    const bf16x8* __restrict__ frags,
    const float* __restrict__ b_ih,
    const float* __restrict__ b_hh,
    float*       __restrict__ out,
    int B)
{
    __shared__ __align__(16) unsigned char xs_raw[ROWS * 256];  // bf16 [64][128] swizzled
    __shared__ __align__(16) unsigned char hf_raw[ROWS * 512];  // f32  [64][128] swizzled
    __shared__ int ids[ROWS];

    const int wave = threadIdx.x >> 6;
    const int lane = threadIdx.x & 63;
    const int l15  = lane & 15;
    const int lg   = lane >> 4;
    const int col  = wave * 16 + l15;

    // register-resident weight fragments (24 coalesced 16B loads)
    bf16x8 bfrag[6][4];
    #pragma unroll
    for (int g = 0; g < 6; ++g)
        #pragma unroll
        for (int ks = 0; ks < 4; ++ks)
            bfrag[g][ks] = frags[((wave * 6 + g) * 4 + ks) * 64 + lane];

    const float bi_r = b_ih[col], bi_z = b_ih[GRU_H + col], bi_n = b_ih[2 * GRU_H + col];
    const float bh_r = b_hh[col], bh_z = b_hh[GRU_H + col], bh_n = b_hh[2 * GRU_H + col];

    const int nchunks = (B + ROWS - 1) / ROWS;
    for (int c = blockIdx.x; c < nchunks; c += gridDim.x) {
        const int rb = c * ROWS;

        // stage h (f32, 2048 float4 slots) — swizzle: chunk16B byte ^= (row&7)<<4
        #pragma unroll
        for (int s = 0; s < 4; ++s) {
            const int slot = threadIdx.x + s * 512;   // 0..2047
            const int row  = slot >> 5;
            const int c4   = slot & 31;
            const int grow = rb + row;
            float4 v = {0.f, 0.f, 0.f, 0.f};
            if (grow < B) {
                const int gid = node_ids[grow];
                if (c4 == 0) ids[row] = gid;
                v = *reinterpret_cast<const float4*>(&memory[(size_t)gid * GRU_H + c4 * 4]);
            }
            *reinterpret_cast<float4*>(&hf_raw[row * 512 + ((c4 * 16) ^ ((row & 7) << 4))]) = v;
        }
        // stage x (bf16, 1024 bf16x8 slots)
        #pragma unroll
        for (int s = 0; s < 2; ++s) {
            const int slot = threadIdx.x + s * 512;   // 0..1023
            const int row  = slot >> 4;
            const int c8   = slot & 15;
            const int grow = rb + row;
            bf16x8 v;
            if (grow < B) {
                const float* p = &messages[(size_t)grow * GRU_H + c8 * 8];
                float4 a = *reinterpret_cast<const float4*>(p);
                float4 b = *reinterpret_cast<const float4*>(p + 4);
                v = cvt8(a, b);
            } else {
                #pragma unroll
                for (int j = 0; j < 8; ++j) v[j] = (__bf16)0.f;
            }
            *reinterpret_cast<bf16x8*>(&xs_raw[row * 256 + ((c8 * 16) ^ ((row & 7) << 4))]) = v;
        }
        __syncthreads();

        #pragma unroll
        for (int sub = 0; sub < 4; ++sub) {
            const int rbase = sub * 16;
            const int arow  = rbase + l15;
            const int sw    = (arow & 7) << 4;

            bf16x8 ax[4], ah[4];
            #pragma unroll
            for (int ks = 0; ks < 4; ++ks) {
                ax[ks] = *reinterpret_cast<const bf16x8*>(
                    &xs_raw[arow * 256 + (((ks * 4 + lg) * 16) ^ sw)]);
                const int c4a = ks * 8 + lg * 2;
                float4 f0 = *reinterpret_cast<const float4*>(
                    &hf_raw[arow * 512 + ((c4a * 16) ^ sw)]);
                float4 f1 = *reinterpret_cast<const float4*>(
                    &hf_raw[arow * 512 + (((c4a + 1) * 16) ^ sw)]);
                ah[ks] = cvt8(f0, f1);
            }

            f32x4 acc[6];
            #pragma unroll
            for (int g = 0; g < 6; ++g) acc[g] = (f32x4){0.f, 0.f, 0.f, 0.f};

            #pragma unroll
            for (int ks = 0; ks < 4; ++ks) {
                acc[0] = __builtin_amdgcn_mfma_f32_16x16x32_bf16(ax[ks], bfrag[0][ks], acc[0], 0, 0, 0);
                acc[1] = __builtin_amdgcn_mfma_f32_16x16x32_bf16(ax[ks], bfrag[1][ks], acc[1], 0, 0, 0);
                acc[2] = __builtin_amdgcn_mfma_f32_16x16x32_bf16(ax[ks], bfrag[2][ks], acc[2], 0, 0, 0);
                acc[3] = __builtin_amdgcn_mfma_f32_16x16x32_bf16(ah[ks], bfrag[3][ks], acc[3], 0, 0, 0);
                acc[4] = __builtin_amdgcn_mfma_f32_16x16x32_bf16(ah[ks], bfrag[4][ks], acc[4], 0, 0, 0);
                acc[5] = __builtin_amdgcn_mfma_f32_16x16x32_bf16(ah[ks], bfrag[5][ks], acc[5], 0, 0, 0);
            }

            // D layout: col=l15, row=lg*4+r
            #pragma unroll
            for (int r = 0; r < 4; ++r) {
                const int row  = rbase + lg * 4 + r;
                const int grow = rb + row;
                if (grow < B) {
                    const int gid = ids[row];
                    const float h = *reinterpret_cast<const float*>(
                        &hf_raw[row * 512 + ((((col >> 2) * 16) ^ ((row & 7) << 4)) + (col & 3) * 4)]);
                    const float rg = sigmoidf_((acc[0][r] + bi_r) + (acc[3][r] + bh_r));
                    const float zg = sigmoidf_((acc[1][r] + bi_z) + (acc[4][r] + bh_z));
                    const float ng = tanhf_((acc[2][r] + bi_n) + rg * (acc[5][r] + bh_n));
                    out[(size_t)gid * GRU_H + col] = (1.f - zg) * ng + zg * h;
                }
            }
        }
        __syncthreads();
    }
}

extern "C" void kernel_launch(void* const* d_in, const int* in_sizes, int n_in,
                              void* d_out, int out_size, void* d_ws, size_t ws_size,
                              hipStream_t stream) {
    const int*   node_ids = (const int*)d_in[0];
    const float* messages = (const float*)d_in[1];
    const float* memory   = (const float*)d_in[2];
    const float* W_ih     = (const float*)d_in[3];
    const float* W_hh     = (const float*)d_in[4];
    const float* b_ih     = (const float*)d_in[5];
    const float* b_hh     = (const float*)d_in[6];
    float* out = (float*)d_out;

    const int B = in_sizes[0];                  // 100000
    const int N = in_sizes[2] / GRU_H;          // 500000

    int*    flag  = (int*)d_ws;
    bf16x8* frags = (bf16x8*)((char*)d_ws + 1024);

    // 1) weights -> bf16 fragments (+ flag=0)
    convert_weights<<<24, 512, 0, stream>>>(W_ih, W_hh, frags, flag);
    // 2) arange check
    check_arange<<<256, 256, 0, stream>>>(node_ids, B, flag);
    // 3) pass-through copy (skips rows <B when arange confirmed)
    const size_t n4 = (size_t)N * GRU_H / 4;
    const size_t skip4 = (size_t)B * GRU_H / 4;
    copy_skip<<<2048, 256, 0, stream>>>((const float4*)memory, (float4*)out, n4, skip4, flag);
    // 4) GRU update + scatter
    const int nchunks = (B + ROWS - 1) / ROWS;
    int grid = nchunks < 512 ? nchunks : 512;
    gru_update_kernel<<<grid, 512, 0, stream>>>(node_ids, messages, memory,
                                                frags, b_ih, b_hh, out, B);
}